// Round 10
// baseline (1746.520 us; speedup 1.0000x reference)
//
#include <hip/hip_runtime.h>
#include <hip/hip_cooperative_groups.h>

namespace cg = cooperative_groups;

#define NPTS 4096
#define NB 4
#define NROWS (NB*NPTS)       // 16384
#define EPSV 1e-5f
#define THR 1.067f            // d2 cutoff: sim==+0.0 exactly for d2>1.0667 (h^2 underflow)
#define C2 (-72.134752f)      // -50*log2(e); sim = (2^(C2*d))^2 = exp(-100 d)
#define DSCALE 61900.0f       // d in [0,1.0333) -> u16 (max 63958)
#define DINV (1.0f/61900.0f)
#define CDQ (C2*DINV)         // exp2 arg per d_q count
#define MAXRCAP 1024          // LDS row buffer; max degree ~985 (origin point) < 1024

typedef unsigned short u16;
typedef unsigned int u32;
typedef unsigned long long ull;

__device__ __forceinline__ float quad_d2(float4 a, float4 g) {
    float cr = fmaf(a.z, g.z, fmaf(a.y, g.y, a.x * g.x));
    return fmaf(-2.0f, cr, a.w + g.w);  // pinned FMA pattern, identical everywhere
}

// ---------------- init: pack float4(x,y,z,|p|^2), u=v=1 ---------------------
__global__ void init_kernel(const float* __restrict__ pred,
                            const float* __restrict__ gt,
                            float4* __restrict__ A4, float4* __restrict__ B4,
                            float* __restrict__ u, float* __restrict__ v) {
    int t = blockIdx.x * 256 + threadIdx.x;
    if (t < NROWS) {
        float x = pred[3*t], y = pred[3*t+1], z = pred[3*t+2];
        A4[t] = make_float4(x, y, z, (x*x + y*y) + z*z);
        x = gt[3*t]; y = gt[3*t+1]; z = gt[3*t+2];
        B4[t] = make_float4(x, y, z, (x*x + y*y) + z*z);
        u[t] = 1.0f; v[t] = 1.0f;
    }
}

// ---------------- fused fill: j-scan into LDS, epilogue packs padded CSR ----
// grid 1024 x block 1024: [0,512) dir A->B, [512,1024) dir B->A.
// 32 rows/block, 2 rows/wave; jbuf cap 1024/row (exact: max degree ~985).
__global__ __launch_bounds__(1024) void fill_kernel(
        const float4* __restrict__ A4, const float4* __restrict__ B4,
        u32* __restrict__ ee, int* __restrict__ cnt, int rcapLog) {
    __shared__ float4 tile[NPTS];                // 64 KB
    __shared__ u16 jbuf[32 * MAXRCAP];           // 64 KB
    int tid = threadIdx.x, wave = tid >> 6, lane = tid & 63;
    int bid = blockIdx.x;
    int dir = bid >> 9;
    int rbase = (bid & 511) * 32;
    int b = rbase >> 12;
    const float4* RowPts = dir ? B4 : A4;
    const float4* ColPts = dir ? A4 : B4;
    int r0 = __builtin_amdgcn_readfirstlane(rbase + wave * 2);
    float4 a0 = RowPts[r0], a1 = RowPts[r0 + 1];
    #pragma unroll
    for (int k = 0; k < 4; ++k)
        tile[tid + k*1024] = ColPts[b*NPTS + tid + k*1024];
    __syncthreads();
    int lrow = wave * 2;
    int o0 = 0, o1 = 0;
    for (int jt = 0; jt < NPTS; jt += 64) {
        float4 g = tile[jt + lane];
        u32 j = (u32)(jt + lane);
        {
            bool keep = quad_d2(a0, g) < THR;
            ull m = __ballot(keep);
            if (keep) {
                int pre = __builtin_amdgcn_mbcnt_hi((unsigned)(m >> 32),
                           __builtin_amdgcn_mbcnt_lo((unsigned)m, 0));
                int idx = o0 + pre;
                if (idx < MAXRCAP) jbuf[lrow * MAXRCAP + idx] = (u16)j;
            }
            o0 += __popcll(m);
        }
        {
            bool keep = quad_d2(a1, g) < THR;
            ull m = __ballot(keep);
            if (keep) {
                int pre = __builtin_amdgcn_mbcnt_hi((unsigned)(m >> 32),
                           __builtin_amdgcn_mbcnt_lo((unsigned)m, 0));
                int idx = o1 + pre;
                if (idx < MAXRCAP) jbuf[(lrow + 1) * MAXRCAP + idx] = (u16)j;
            }
            o1 += __popcll(m);
        }
    }
    // epilogue: dense 64-lane packing; wave-private rows, no barrier needed
    int rcap = 1 << rcapLog;
    #pragma unroll
    for (int i = 0; i < 2; ++i) {
        int oi = i ? o1 : o0;
        int n = oi < rcap ? oi : rcap;
        int rd = dir * NROWS + r0 + i;
        u32 outbase = (u32)rd << rcapLog;
        for (int t = lane; t < n; t += 64) {
            int j = jbuf[(lrow + i) * MAXRCAP + t];
            float4 g = tile[j];
            float d2 = quad_d2(i ? a1 : a0, g);
            float d = __builtin_amdgcn_sqrtf(fmaxf(d2, 0.0f));
            u32 dq = (u32)fmaf(d, DSCALE, 0.5f);
            ee[outbase + t] = (dq << 16) | (u32)j;
        }
        if (lane == 0) cnt[rd] = n;
    }
}

// ---------------- one Sinkhorn half-iteration (device fn) -------------------
__device__ __forceinline__ void half_pass(
        const int* __restrict__ cnt, const u32* __restrict__ ee,
        float* __restrict__ target, const float* ss,
        int rowBase, int robase, int wave, int lane, int rcapLog) {
    for (int rr = 0; rr < 4; ++rr) {
        int r = __builtin_amdgcn_readfirstlane(rowBase + wave*4 + rr);
        int rd = robase + r;
        int n = cnt[rd];
        u32 base = (u32)rd << rcapLog;
        float ac0 = 0.f, ac1 = 0.f, ac2 = 0.f, ac3 = 0.f;
        int t = lane;
        for (; t + 192 < n; t += 256) {          // 4-way MLP
            u32 e0 = ee[base+t], e1 = ee[base+t+64], e2 = ee[base+t+128], e3 = ee[base+t+192];
            float h0 = __builtin_amdgcn_exp2f((float)(e0 >> 16) * CDQ);
            float h1 = __builtin_amdgcn_exp2f((float)(e1 >> 16) * CDQ);
            float h2 = __builtin_amdgcn_exp2f((float)(e2 >> 16) * CDQ);
            float h3 = __builtin_amdgcn_exp2f((float)(e3 >> 16) * CDQ);
            ac0 = fmaf(h0 * h0, ss[e0 & 0xFFFF], ac0);
            ac1 = fmaf(h1 * h1, ss[e1 & 0xFFFF], ac1);
            ac2 = fmaf(h2 * h2, ss[e2 & 0xFFFF], ac2);
            ac3 = fmaf(h3 * h3, ss[e3 & 0xFFFF], ac3);
        }
        for (; t < n; t += 64) {
            u32 e0 = ee[base+t];
            float h0 = __builtin_amdgcn_exp2f((float)(e0 >> 16) * CDQ);
            ac0 = fmaf(h0 * h0, ss[e0 & 0xFFFF], ac0);
        }
        float acc = (ac0 + ac1) + (ac2 + ac3);
        #pragma unroll
        for (int off = 32; off > 0; off >>= 1) acc += __shfl_xor(acc, off);
        float to = target[r];
        float tn = to / fmaf(to, acc, EPSV);
        if (lane == 0) target[r] = tn;
    }
}

// ---------------- cooperative mega-kernel: 10 halves + final + reduce -------
// grid 512 x block 512 (2 blocks/CU co-resident). 32 rows/block.
__global__ __launch_bounds__(512) void sinkhorn_kernel(
        const int* __restrict__ cnt, const u32* __restrict__ ee,
        float* __restrict__ u, float* __restrict__ v,
        float* __restrict__ partial, float* __restrict__ out, int rcapLog) {
    cg::grid_group grid = cg::this_grid();
    __shared__ float ss[NPTS];                   // 16 KB
    __shared__ float wpart[8];
    int tid = threadIdx.x, wave = tid >> 6, lane = tid & 63;
    int rowBase = blockIdx.x * 32;
    int b = rowBase >> 12;
    for (int it = 0; it < 5; ++it) {
        // row half: u <- u / (u * (S_A v) + eps)
        #pragma unroll
        for (int k = 0; k < 2; ++k)
            ((float4*)ss)[tid + k*512] = ((const float4*)(v + b*NPTS))[tid + k*512];
        __syncthreads();
        half_pass(cnt, ee, u, ss, rowBase, 0, wave, lane, rcapLog);
        __threadfence();
        grid.sync();
        // col half: v <- v / (v * (S_B u) + eps)
        #pragma unroll
        for (int k = 0; k < 2; ++k)
            ((float4*)ss)[tid + k*512] = ((const float4*)(u + b*NPTS))[tid + k*512];
        __syncthreads();
        half_pass(cnt, ee, v, ss, rowBase, NROWS, wave, lane, rcapLog);
        __threadfence();
        grid.sync();
    }
    // ---------------- final: top-5 per row -> block partial -----------------
    #pragma unroll
    for (int k = 0; k < 2; ++k)
        ((float4*)ss)[tid + k*512] = ((const float4*)(v + b*NPTS))[tid + k*512];
    __syncthreads();
    float wsum = 0.0f;
    for (int rr = 0; rr < 4; ++rr) {
        int r = __builtin_amdgcn_readfirstlane(rowBase + wave*4 + rr);
        int n = cnt[r];                          // dir-A rows
        u32 base = (u32)r << rcapLog;
        float q0=-1.f,q1=-1.f,q2=-1.f,q3=-1.f,q4=-1.f;
        float d0=0.f,d1=0.f,d2v=0.f,d3=0.f,d4=0.f;
        for (int t = lane; t < n; t += 64) {
            u32 ea = ee[base + t];
            float fdq = (float)(ea >> 16);
            float h = __builtin_amdgcn_exp2f(fdq * CDQ);
            float q = (h * h) * ss[ea & 0xFFFF];
            if (q > q4) {                        // pure-VALU insert
                float dv = fdq * DINV;
                q4 = q; d4 = dv;
                if (q4 > q3) { float t1=q3;q3=q4;q4=t1; float t2=d3;d3=d4;d4=t2; }
                if (q3 > q2) { float t1=q2;q2=q3;q3=t1; float t2=d2v;d2v=d3;d3=t2; }
                if (q2 > q1) { float t1=q1;q1=q2;q2=t1; float t2=d1;d1=d2v;d2v=t2; }
                if (q1 > q0) { float t1=q0;q0=q1;q1=t1; float t2=d0;d0=d1;d1=t2; }
            }
        }
        float S0 = 0.0f, S1 = 0.0f;
        #define TOURN_ROUND                                                  \
        {                                                                    \
            float mq = q0, md = d0;                                          \
            _Pragma("unroll")                                                \
            for (int off = 1; off < 64; off <<= 1) {                         \
                float oq = __shfl_xor(mq, off), od = __shfl_xor(md, off);    \
                if (oq > mq) { mq = oq; md = od; }                           \
            }                                                                \
            if (mq > 0.0f) { S0 += mq; S1 = fmaf(mq, md, S1); }              \
            ull ball = __ballot(q0 == mq);                                   \
            int winner = __ffsll(ball) - 1;                                  \
            if (lane == winner) {                                            \
                q0=q1; d0=d1; q1=q2; d1=d2v; q2=q3; d2v=d3; q3=q4; d3=d4;    \
                q4=-1.f; d4=0.f;                                             \
            }                                                                \
        }
        TOURN_ROUND TOURN_ROUND TOURN_ROUND TOURN_ROUND TOURN_ROUND
        #undef TOURN_ROUND
        float uo = u[r];
        wsum += (uo * S1) / fmaf(uo, S0, EPSV);
    }
    if (lane == 0) wpart[wave] = wsum;
    __syncthreads();
    if (tid == 0) {
        float s = 0.0f;
        #pragma unroll
        for (int i = 0; i < 8; ++i) s += wpart[i];
        partial[blockIdx.x] = s;
    }
    __threadfence();
    grid.sync();
    // ---------------- reduce on block 0 -------------------------------------
    if (blockIdx.x == 0) {
        float s = partial[tid];                  // 512 partials, 512 threads
        #pragma unroll
        for (int off = 32; off > 0; off >>= 1) s += __shfl_xor(s, off);
        if (lane == 0) wpart[wave] = s;
        __syncthreads();
        if (tid == 0) {
            float t = 0.0f;
            #pragma unroll
            for (int i = 0; i < 8; ++i) t += wpart[i];
            out[0] = t * (1.0f / NB);
        }
    }
}

extern "C" void kernel_launch(void* const* d_in, const int* in_sizes, int n_in,
                              void* d_out, int out_size, void* d_ws, size_t ws_size,
                              hipStream_t stream) {
    (void)in_sizes; (void)n_in; (void)out_size;
    const float* pred = (const float*)d_in[0];
    const float* gt   = (const float*)d_in[1];
    char* p = (char*)d_ws;

    float4* A4      = (float4*)p;   p += 262144;
    float4* B4      = (float4*)p;   p += 262144;
    float*  u       = (float*)p;    p += 65536;
    float*  v       = (float*)p;    p += 65536;
    int*    cnt     = (int*)p;      p += 131072;             // 32768 ints
    float*  partial = (float*)p;    p += 4096;               // 512 + pad
    u32*    ee      = (u32*)p;
    size_t fixed    = (size_t)(p - (char*)d_ws);
    // exact CSR needs rcap=1024 (128 MB); fall back to 512 if ws too small
    // (ws_size is launch-invariant -> deterministic, graph-capture-safe)
    int rcapLog = (ws_size >= fixed + (size_t)2*NROWS*1024*4) ? 10 : 9;
    float* out = (float*)d_out;

    hipLaunchKernelGGL(init_kernel, dim3(64), dim3(256), 0, stream,
                       pred, gt, A4, B4, u, v);
    hipLaunchKernelGGL(fill_kernel, dim3(1024), dim3(1024), 0, stream,
                       A4, B4, ee, cnt, rcapLog);
    void* args[] = {(void*)&cnt, (void*)&ee, (void*)&u, (void*)&v,
                    (void*)&partial, (void*)&out, (void*)&rcapLog};
    hipLaunchCooperativeKernel((const void*)sinkhorn_kernel,
                               dim3(512), dim3(512), args, 0, stream);
}

// Round 11
// 256.636 us; speedup vs baseline: 6.8054x; 6.8054x over previous
//
#include <hip/hip_runtime.h>

#define NPTS 4096
#define NB 4
#define NROWS (NB*NPTS)       // 16384
#define EPSV 1e-5f
#define THR 1.067f            // d2 cutoff: sim==+0.0 exactly for d2>1.0667 (h^2 underflow)
#define C2 (-72.134752f)      // -50*log2(e); sim = (2^(C2*d))^2 = exp(-100 d)
#define DSCALE 61900.0f       // d in [0,1.0333) -> u16 (max 63958)
#define DINV (1.0f/61900.0f)
#define CDQ (C2*DINV)         // exp2 arg per d_q count
#define PHCOLS 2048           // columns staged per fill phase
#define JCAP 1024             // phase-local jbuf cap (>= max row degree ~985)

typedef unsigned short u16;
typedef unsigned int u32;
typedef unsigned long long ull;

__device__ __forceinline__ float quad_d2(float4 a, float4 g) {
    float cr = fmaf(a.z, g.z, fmaf(a.y, g.y, a.x * g.x));
    return fmaf(-2.0f, cr, a.w + g.w);  // pinned FMA pattern, identical everywhere
}

// ---------------- init: pack float4(x,y,z,|p|^2), u=v=1 ---------------------
__global__ void init_kernel(const float* __restrict__ pred,
                            const float* __restrict__ gt,
                            float4* __restrict__ A4, float4* __restrict__ B4,
                            float* __restrict__ u, float* __restrict__ v) {
    int t = blockIdx.x * 256 + threadIdx.x;
    if (t < NROWS) {
        float x = pred[3*t], y = pred[3*t+1], z = pred[3*t+2];
        A4[t] = make_float4(x, y, z, (x*x + y*y) + z*z);
        x = gt[3*t]; y = gt[3*t+1]; z = gt[3*t+2];
        B4[t] = make_float4(x, y, z, (x*x + y*y) + z*z);
        u[t] = 1.0f; v[t] = 1.0f;
    }
}

// ---------------- fill: 2-phase tile, LDS j-scan, per-phase pack epilogue ---
// grid 2048 x block 1024: [0,1024) dir A->B, [1024,2048) dir B->A.
// 16 rows/block, 1 row/wave. LDS = 32KB tile + 32KB jbuf -> 2 blocks/CU.
__global__ __launch_bounds__(1024) void fill_kernel(
        const float4* __restrict__ A4, const float4* __restrict__ B4,
        u32* __restrict__ ee, int* __restrict__ cnt, int rcapLog) {
    __shared__ float4 tile[PHCOLS];              // 32 KB
    __shared__ u16 jbuf[16 * JCAP];              // 32 KB
    int tid = threadIdx.x, wave = tid >> 6, lane = tid & 63;
    int bid = blockIdx.x;
    int dir = bid >> 10;
    int r = (bid & 1023) * 16 + wave;            // this wave's row
    int b = (bid & 1023) >> 8;                   // batch = row/4096
    const float4* RowPts = dir ? B4 : A4;
    const float4* ColPts = dir ? A4 : B4;
    int rd = dir * NROWS + r;
    float4 a = RowPts[r];
    int rcap = 1 << rcapLog;
    u32 outbase = (u32)rd << rcapLog;
    int o = 0;                                    // running row count
    u16* jb = jbuf + wave * JCAP;
    for (int phase = 0; phase < NPTS / PHCOLS; ++phase) {
        __syncthreads();                          // prior epilogue done w/ tile
        tile[tid]        = ColPts[b*NPTS + phase*PHCOLS + tid];
        tile[tid + 1024] = ColPts[b*NPTS + phase*PHCOLS + tid + 1024];
        __syncthreads();
        // scan: push phase-local j of survivors into wave-private jbuf
        int pc = 0;
        for (int jt = 0; jt < PHCOLS; jt += 64) {
            float4 g = tile[jt + lane];
            bool keep = quad_d2(a, g) < THR;
            ull m = __ballot(keep);
            if (keep) {
                int pre = __builtin_amdgcn_mbcnt_hi((unsigned)(m >> 32),
                           __builtin_amdgcn_mbcnt_lo((unsigned)m, 0));
                int idx = pc + pre;
                if (idx < JCAP) jb[idx] = (u16)(jt + lane);
            }
            pc += __popcll(m);
        }
        if (pc > JCAP) pc = JCAP;
        // epilogue: dense 64-lane pack+store while tile is resident
        for (int t = lane; t < pc; t += 64) {
            int jl = jb[t];
            float4 g = tile[jl];
            float d2 = quad_d2(a, g);
            float d = __builtin_amdgcn_sqrtf(fmaxf(d2, 0.0f));
            u32 dq = (u32)fmaf(d, DSCALE, 0.5f);
            int oi = o + t;
            if (oi < rcap)
                ee[outbase + oi] = (dq << 16) | (u32)(phase * PHCOLS + jl);
        }
        o += pc;
    }
    if (o > rcap) o = rcap;
    if (lane == 0) cnt[rd] = o;
}

// ---------------- Sinkhorn half-iteration: gather walk, no atomics ----------
// target[r] = target[r] / (target[r] * sum_j sim(r,j)*source[j] + eps)
// grid 1024 x block 256: 16 rows/block, 4 rows/wave; 16KB LDS -> 4+ blocks/CU.
__global__ __launch_bounds__(256) void pass_kernel(
        const int* __restrict__ cnt, int dir, const u32* __restrict__ ee,
        float* __restrict__ target, const float* __restrict__ source, int rcapLog) {
    __shared__ float ss[NPTS];                   // 16 KB
    int tid = threadIdx.x;
    int rowBase = blockIdx.x * 16;
    int b = rowBase >> 12;
    #pragma unroll
    for (int k = 0; k < 4; ++k)
        ((float4*)ss)[tid + k*256] = ((const float4*)(source + b*NPTS))[tid + k*256];
    __syncthreads();
    int wave = tid >> 6, lane = tid & 63;
    for (int rr = 0; rr < 4; ++rr) {
        int r = __builtin_amdgcn_readfirstlane(rowBase + wave*4 + rr);
        int rd = dir * NROWS + r;
        int n = cnt[rd];
        u32 base = (u32)rd << rcapLog;
        float ac0 = 0.f, ac1 = 0.f, ac2 = 0.f, ac3 = 0.f;
        int t = lane;
        for (; t + 192 < n; t += 256) {          // 4-way MLP
            u32 e0 = ee[base+t], e1 = ee[base+t+64], e2 = ee[base+t+128], e3 = ee[base+t+192];
            float h0 = __builtin_amdgcn_exp2f((float)(e0 >> 16) * CDQ);
            float h1 = __builtin_amdgcn_exp2f((float)(e1 >> 16) * CDQ);
            float h2 = __builtin_amdgcn_exp2f((float)(e2 >> 16) * CDQ);
            float h3 = __builtin_amdgcn_exp2f((float)(e3 >> 16) * CDQ);
            ac0 = fmaf(h0 * h0, ss[e0 & 0xFFFF], ac0);
            ac1 = fmaf(h1 * h1, ss[e1 & 0xFFFF], ac1);
            ac2 = fmaf(h2 * h2, ss[e2 & 0xFFFF], ac2);
            ac3 = fmaf(h3 * h3, ss[e3 & 0xFFFF], ac3);
        }
        for (; t < n; t += 64) {
            u32 e0 = ee[base+t];
            float h0 = __builtin_amdgcn_exp2f((float)(e0 >> 16) * CDQ);
            ac0 = fmaf(h0 * h0, ss[e0 & 0xFFFF], ac0);
        }
        float acc = (ac0 + ac1) + (ac2 + ac3);
        #pragma unroll
        for (int off = 32; off > 0; off >>= 1) acc += __shfl_xor(acc, off);
        float to = target[r];
        float tn = to / fmaf(to, acc, EPSV);
        if (lane == 0) target[r] = tn;
    }
}

// ---------------- final: top-5 per row -> per-block partial (no atomics) ----
__global__ __launch_bounds__(256) void final_kernel(
        const int* __restrict__ cnt, const u32* __restrict__ ee,
        const float* __restrict__ u, const float* __restrict__ v,
        float* __restrict__ partial, int rcapLog) {
    __shared__ float vs[NPTS];                   // 16 KB
    __shared__ float wpart[4];
    int tid = threadIdx.x;
    int rowBase = blockIdx.x * 16;               // grid 1024
    int b = rowBase >> 12;
    #pragma unroll
    for (int k = 0; k < 4; ++k)
        ((float4*)vs)[tid + k*256] = ((const float4*)(v + b*NPTS))[tid + k*256];
    __syncthreads();
    int wave = tid >> 6, lane = tid & 63;
    float wsum = 0.0f;
    for (int rr = 0; rr < 4; ++rr) {
        int r = __builtin_amdgcn_readfirstlane(rowBase + wave*4 + rr);
        int n = cnt[r];                          // dir-A rows
        u32 base = (u32)r << rcapLog;
        float q0=-1.f,q1=-1.f,q2=-1.f,q3=-1.f,q4=-1.f;
        float d0=0.f,d1=0.f,d2v=0.f,d3=0.f,d4=0.f;
        for (int t = lane; t < n; t += 64) {
            u32 ea = ee[base + t];
            float fdq = (float)(ea >> 16);
            float h = __builtin_amdgcn_exp2f(fdq * CDQ);
            float q = (h * h) * vs[ea & 0xFFFF];
            if (q > q4) {                        // pure-VALU insert
                float dv = fdq * DINV;
                q4 = q; d4 = dv;
                if (q4 > q3) { float t1=q3;q3=q4;q4=t1; float t2=d3;d3=d4;d4=t2; }
                if (q3 > q2) { float t1=q2;q2=q3;q3=t1; float t2=d2v;d2v=d3;d3=t2; }
                if (q2 > q1) { float t1=q1;q1=q2;q2=t1; float t2=d1;d1=d2v;d2v=t2; }
                if (q1 > q0) { float t1=q0;q0=q1;q1=t1; float t2=d0;d0=d1;d1=t2; }
            }
        }
        float S0 = 0.0f, S1 = 0.0f;
        #define TOURN_ROUND                                                  \
        {                                                                    \
            float mq = q0, md = d0;                                          \
            _Pragma("unroll")                                                \
            for (int off = 1; off < 64; off <<= 1) {                         \
                float oq = __shfl_xor(mq, off), od = __shfl_xor(md, off);    \
                if (oq > mq) { mq = oq; md = od; }                           \
            }                                                                \
            if (mq > 0.0f) { S0 += mq; S1 = fmaf(mq, md, S1); }              \
            ull ball = __ballot(q0 == mq);                                   \
            int winner = __ffsll(ball) - 1;                                  \
            if (lane == winner) {                                            \
                q0=q1; d0=d1; q1=q2; d1=d2v; q2=q3; d2v=d3; q3=q4; d3=d4;    \
                q4=-1.f; d4=0.f;                                             \
            }                                                                \
        }
        TOURN_ROUND TOURN_ROUND TOURN_ROUND TOURN_ROUND TOURN_ROUND
        #undef TOURN_ROUND
        float uo = u[r];
        wsum += (uo * S1) / fmaf(uo, S0, EPSV);
    }
    if (lane == 0) wpart[wave] = wsum;
    __syncthreads();
    if (tid == 0)
        partial[blockIdx.x] = ((wpart[0] + wpart[1]) + wpart[2]) + wpart[3];
}

// ---------------- reduce: 1024 partials -> out[0] ---------------------------
__global__ void reduce_kernel(const float* __restrict__ partial,
                              float* __restrict__ out) {
    __shared__ float ws[4];
    int tid = threadIdx.x;                       // 1 block, 256 threads
    float s = ((partial[tid] + partial[tid+256]) +
               (partial[tid+512] + partial[tid+768]));
    #pragma unroll
    for (int off = 32; off > 0; off >>= 1) s += __shfl_xor(s, off);
    if ((tid & 63) == 0) ws[tid >> 6] = s;
    __syncthreads();
    if (tid == 0) out[0] = (((ws[0] + ws[1]) + ws[2]) + ws[3]) * (1.0f / NB);
}

extern "C" void kernel_launch(void* const* d_in, const int* in_sizes, int n_in,
                              void* d_out, int out_size, void* d_ws, size_t ws_size,
                              hipStream_t stream) {
    (void)in_sizes; (void)n_in; (void)out_size;
    const float* pred = (const float*)d_in[0];
    const float* gt   = (const float*)d_in[1];
    char* p = (char*)d_ws;

    float4* A4      = (float4*)p;   p += 262144;
    float4* B4      = (float4*)p;   p += 262144;
    float*  u       = (float*)p;    p += 65536;
    float*  v       = (float*)p;    p += 65536;
    int*    cnt     = (int*)p;      p += 131072;             // 32768 ints
    float*  partial = (float*)p;    p += 4096;               // 1024 floats
    u32*    ee      = (u32*)p;
    size_t fixed    = (size_t)(p - (char*)d_ws);
    // exact CSR needs rcap=1024 (128 MB); R10 confirmed ws fits (absmax=4 =>
    // rcapLog was 10). Deterministic fallback kept for safety.
    int rcapLog = (ws_size >= fixed + (size_t)2*NROWS*1024*4) ? 10 : 9;
    float* out = (float*)d_out;

    hipLaunchKernelGGL(init_kernel, dim3(64), dim3(256), 0, stream,
                       pred, gt, A4, B4, u, v);
    hipLaunchKernelGGL(fill_kernel, dim3(2048), dim3(1024), 0, stream,
                       A4, B4, ee, cnt, rcapLog);
    for (int it = 0; it < 5; ++it) {
        hipLaunchKernelGGL(pass_kernel, dim3(1024), dim3(256), 0, stream,
                           cnt, 0, ee, u, v, rcapLog);   // row: u <- f(u; v)
        hipLaunchKernelGGL(pass_kernel, dim3(1024), dim3(256), 0, stream,
                           cnt, 1, ee, v, u, rcapLog);   // col: v <- f(v; u)
    }
    hipLaunchKernelGGL(final_kernel, dim3(1024), dim3(256), 0, stream,
                       cnt, ee, u, v, partial, rcapLog);
    hipLaunchKernelGGL(reduce_kernel, dim3(1), dim3(256), 0, stream, partial, out);
}